// Round 5
// baseline (269.810 us; speedup 1.0000x reference)
//
#include <hip/hip_runtime.h>
#include <hip/hip_bf16.h>

typedef __bf16 bf16;
typedef __attribute__((ext_vector_type(8))) __bf16 bf16x8;
typedef __attribute__((ext_vector_type(4))) __bf16 bf16x4;
typedef __attribute__((ext_vector_type(2))) __bf16 bf16x2;
typedef __attribute__((ext_vector_type(16))) float floatx16;
typedef unsigned int u32;

#define MFMA32(a, b, c) __builtin_amdgcn_mfma_f32_32x32x16_bf16((a), (b), (c), 0, 0, 0)

#define DIM 384
#define T1 3136   // 56*56
#define T2 784    // 28*28
#define T2P 832   // padded t for Vt columns
#define B_ 8
#define EPSV 1e-5f

__device__ __forceinline__ void gload_lds16(const bf16* g, bf16* l) {
  __builtin_amdgcn_global_load_lds(
      (const __attribute__((address_space(1))) void*)g,
      (__attribute__((address_space(3))) void*)l, 16, 0, 0);
}

__device__ __forceinline__ u32 pk2(float a, float b) {
  bf16x2 t = (bf16x2){(bf16)a, (bf16)b};
  return *reinterpret_cast<u32*>(&t);
}

// ---------------- fused depthwise convs + BN (q stride-1; k,v stride-2) + wcvt ------
__global__ void conv_fused_kernel(const float* __restrict__ x,
    const float* __restrict__ wqc, const float* __restrict__ gq, const float* __restrict__ bq,
    const float* __restrict__ mq, const float* __restrict__ vq,
    const float* __restrict__ wkc, const float* __restrict__ gk, const float* __restrict__ bk,
    const float* __restrict__ mk, const float* __restrict__ vk,
    const float* __restrict__ wvc, const float* __restrict__ gv, const float* __restrict__ bv,
    const float* __restrict__ mv, const float* __restrict__ vvv,
    bf16* __restrict__ qout, bf16* __restrict__ kout, bf16* __restrict__ vout,
    const float* __restrict__ w0, const float* __restrict__ w1,
    const float* __restrict__ w2, const float* __restrict__ w3,
    bf16* __restrict__ d0, bf16* __restrict__ d1,
    bf16* __restrict__ d2, bf16* __restrict__ d3) {
  int blk = blockIdx.x;
  int c = threadIdx.x;           // 0..383
  int gid = blk * DIM + c;
  if (gid < 147456) {            // folded weight conversion (first 384 blocks)
    d0[gid] = (bf16)w0[gid]; d1[gid] = (bf16)w1[gid];
    d2[gid] = (bf16)w2[gid]; d3[gid] = (bf16)w3[gid];
  }
  int xg = blk % 14;
  int y = (blk / 14) % 56;
  int b = blk / (14 * 56);
  int x0 = xg * 4;
  const float* xb = x + (size_t)b * T1 * DIM;
  float in[3][6];
#pragma unroll
  for (int r = 0; r < 3; ++r) {
    int yy = y + r - 1;
#pragma unroll
    for (int cc = 0; cc < 6; ++cc) {
      int xc = x0 + cc - 1;
      in[r][cc] = (yy >= 0 && yy < 56 && xc >= 0 && xc < 56)
                      ? xb[(yy * 56 + xc) * DIM + c] : 0.f;
    }
  }
  // q path
  {
    float wr[9];
#pragma unroll
    for (int i = 0; i < 9; ++i) wr[i] = wqc[c * 9 + i];
    float a = rsqrtf(vq[c] + EPSV) * gq[c];
    float bia = bq[c] - mq[c] * a;
#pragma unroll
    for (int p = 0; p < 4; ++p) {
      float s = 0.f;
#pragma unroll
      for (int r = 0; r < 3; ++r)
#pragma unroll
        for (int dx = 0; dx < 3; ++dx) s += in[r][p + dx] * wr[r * 3 + dx];
      qout[((size_t)b * T1 + y * 56 + x0 + p) * DIM + c] = (bf16)(s * a + bia);
    }
  }
  // kv path (block-uniform branch)
  if ((y & 1) == 0) {
    int y2 = y >> 1;
    float wk9[9], wv9[9];
#pragma unroll
    for (int i = 0; i < 9; ++i) { wk9[i] = wkc[c * 9 + i]; wv9[i] = wvc[c * 9 + i]; }
    float ak = rsqrtf(vk[c] + EPSV) * gk[c];
    float av = rsqrtf(vvv[c] + EPSV) * gv[c];
    float bik = bk[c] - mk[c] * ak;
    float biv = bv[c] - mv[c] * av;
#pragma unroll
    for (int p2 = 0; p2 < 2; ++p2) {
      float sk = 0.f, sv = 0.f;
#pragma unroll
      for (int r = 0; r < 3; ++r)
#pragma unroll
        for (int dx = 0; dx < 3; ++dx) {
          float xv = in[r][2 * p2 + dx];
          sk += xv * wk9[r * 3 + dx];
          sv += xv * wv9[r * 3 + dx];
        }
      size_t o = ((size_t)b * T2 + y2 * 28 + (x0 >> 1) + p2) * DIM + c;
      kout[o] = (bf16)(sk * ak + bik);
      vout[o] = (bf16)(sv * av + biv);
    }
  }
}

// ---------------- GEMM: C[256,128] tile of A[M,384] @ W[384,384]^T -----------------
// R10: 512-thread / 8-wave blocks (2x waves per resident block: occupancy counter
// showed ~1 block/CU across all prior variants -> TLP was the latency-hiding limit),
// 32x32x16 MFMA (R9-verified layouts), BK=64 with 8-chunk XOR swizzle
// (chunk ^= row&7; 128B rows -> bank = chunk only -> 4-way max, was 8-way),
// double-buffered LDS (96 KB), counted vmcnt(6), 6 barrier-pairs (was 12).
#define BK64 64
#define ABUF (256 * BK64)      // elems per A buffer
#define BBUF (128 * BK64)
__device__ __forceinline__
void gemm512_body(const bf16* A, const bf16* Bw, void* out, const float* bias,
                  int mode, float scale, int m0, int n0, int Mrows,
                  bf16* Al, bf16* Bl) {
  int tid = threadIdx.x;
  int w = tid >> 6, lane = tid & 63;
  int wm = w >> 1, wn = w & 1;            // 4 m-bands x 2 n-bands of 64
  int l32 = lane & 31, hi = lane >> 5;

  // staging: per instr 8 rows x 128 B; lane -> (row=lane>>3, chunk=lane&7),
  // source chunk pre-swizzled by row&7 (LDS stays linear; read applies same XOR).
  int arow = lane >> 3;
  int achk = (lane & 7) ^ arow;
  const bf16* ag0 = &A[(size_t)(m0 + w * 32 + arow) * DIM + achk * 8];
  const bf16* bg0 = &Bw[(size_t)(n0 + w * 16 + arow) * DIM + achk * 8];

  floatx16 acc[2][2];
  acc[0][0] = (floatx16)0.f; acc[0][1] = (floatx16)0.f;
  acc[1][0] = (floatx16)0.f; acc[1][1] = (floatx16)0.f;

  auto STAGE = [&](int s) {
    int bi = s & 1;
    int k = s * BK64;
    bf16* ad = Al + bi * ABUF + (w * 32) * BK64;
    bf16* bd = Bl + bi * BBUF + (w * 16) * BK64;
    gload_lds16(ag0 + k, ad);
    gload_lds16(ag0 + (size_t)8 * DIM + k, ad + 8 * BK64);
    gload_lds16(ag0 + (size_t)16 * DIM + k, ad + 16 * BK64);
    gload_lds16(ag0 + (size_t)24 * DIM + k, ad + 24 * BK64);
    gload_lds16(bg0 + k, bd);
    gload_lds16(bg0 + (size_t)8 * DIM + k, bd + 8 * BK64);
  };

  STAGE(0);
  const int NS = DIM / BK64;  // 6
#pragma unroll
  for (int s = 0; s < NS; ++s) {
    const int cb = s & 1;
    if (s + 1 < NS) {
      STAGE(s + 1);                        // safe: buf (s+1)&1 fully read at s-1
      asm volatile("s_waitcnt vmcnt(6)" ::: "memory");  // retire current buf's 6
    } else {
      asm volatile("s_waitcnt vmcnt(0)" ::: "memory");
    }
    __builtin_amdgcn_s_barrier();          // current buffer globally visible
    const bf16* Ac = Al + cb * ABUF;
    const bf16* Bc = Bl + cb * BBUF;
#pragma unroll
    for (int ksp = 0; ksp < 2; ++ksp) {    // two K=32 halves of the K=64 slice
      bf16x8 af[2][2], bfr[2][2];
#pragma unroll
      for (int kh = 0; kh < 2; ++kh) {
        int ks = ksp * 2 + kh;             // 0..3, k elems = ks*16 + hi*8 + j
        int ch = ((ks * 2 + hi) ^ (l32 & 7)) * 8;
#pragma unroll
        for (int mt = 0; mt < 2; ++mt)
          af[mt][kh] = *(const bf16x8*)&Ac[(wm * 64 + mt * 32 + l32) * BK64 + ch];
#pragma unroll
        for (int nt = 0; nt < 2; ++nt)
          bfr[nt][kh] = *(const bf16x8*)&Bc[(wn * 64 + nt * 32 + l32) * BK64 + ch];
      }
#pragma unroll
      for (int kh = 0; kh < 2; ++kh)
#pragma unroll
        for (int mt = 0; mt < 2; ++mt)
#pragma unroll
          for (int nt = 0; nt < 2; ++nt)
            acc[mt][nt] = MFMA32(af[mt][kh], bfr[nt][kh], acc[mt][nt]);
    }
    asm volatile("s_waitcnt lgkmcnt(0)" ::: "memory");  // our reads of buf cb done
    __builtin_amdgcn_s_barrier();
  }
  // epilogue: C layout col=lane&31, row=(r&3)+8*(r>>2)+4*hi (verified m74/m101/R9)
#pragma unroll
  for (int mt = 0; mt < 2; ++mt) {
#pragma unroll
    for (int nt = 0; nt < 2; ++nt) {
      int col = n0 + wn * 64 + nt * 32 + l32;
#pragma unroll
      for (int r = 0; r < 16; ++r) {
        int row = m0 + wm * 64 + mt * 32 + (r & 3) + 8 * (r >> 2) + 4 * hi;
        float v = acc[mt][nt][r];
        if (mode == 3) {
          ((float*)out)[(size_t)row * DIM + col] = v + bias[col];
        } else if (mode == 2) {
          if (row < Mrows) {
            int b = row / T2;
            int t = row - b * T2;
            ((bf16*)out)[((size_t)b * DIM + col) * T2P + t] = (bf16)v;
          }
        } else if (mode == 0) {
          if (row < Mrows) ((bf16*)out)[(size_t)row * DIM + col] = (bf16)v;
        } else {
          ((bf16*)out)[(size_t)row * DIM + col] = (bf16)(v * scale);
        }
      }
    }
  }
}

// Q (294) + K (75) + V (75) tiles, grid padded to 448 = 8*56; bijective XCD chunking
// t=(bx&7)*56+(bx>>3) so each XCD gets a contiguous tile range (A-panel + weights
// L2-resident; perf-only assumption bx%8 = XCD).
__global__ __launch_bounds__(512, 2)
void qkv_gemm_kernel(const bf16* q_act, const bf16* k_act, const bf16* v_act,
                     const bf16* wqb, const bf16* wkb, const bf16* wvb,
                     bf16* Qp, bf16* Kp, bf16* Vtp, float qscale) {
  __shared__ bf16 Al[2 * ABUF];   // 64 KB
  __shared__ bf16 Bl[2 * BBUF];   // 32 KB
  int bx = blockIdx.x;
  int t = (bx & 7) * 56 + (bx >> 3);
  if (t >= 444) return;
  const bf16 *A, *Bw; void* out; int mode, ti, M; float scale = 1.f;
  if (t < 294)      { A = q_act; Bw = wqb; out = Qp;  mode = 1; ti = t;       M = T1 * B_; scale = qscale; }
  else if (t < 369) { A = k_act; Bw = wkb; out = Kp;  mode = 0; ti = t - 294; M = T2 * B_; }
  else              { A = v_act; Bw = wvb; out = Vtp; mode = 2; ti = t - 369; M = T2 * B_; }
  gemm512_body(A, Bw, out, nullptr, mode, scale, (ti / 3) * 256, (ti % 3) * 128, M, Al, Bl);
}

__global__ __launch_bounds__(512, 2)
void last_gemm_kernel(const bf16* A, const bf16* Bw, float* out, const float* bias) {
  __shared__ bf16 Al[2 * ABUF];
  __shared__ bf16 Bl[2 * BBUF];
  int bx = blockIdx.x;
  int t = (bx & 7) * 37 + (bx >> 3);
  if (t >= 294) return;
  gemm512_body(A, Bw, out, bias, 3, 1.f, (t / 3) * 256, (t % 3) * 128, T1 * B_, Al, Bl);
}

// ---------------- flash attention, S^T/O^T form, 32x32 MFMA, in-register P --------
// R9 (proven): swapped QK^T lands P in the PV B-operand lane; exp2 in-reg ->
// bf16x2 pack -> __shfl_xor(32) -> PV. No P LDS. 16 KB LDS, launch_bounds(256,4).
__global__ __launch_bounds__(256, 4)
void attn_kernel(const bf16* __restrict__ Qp, const bf16* __restrict__ Kp,
                 const bf16* __restrict__ Vt, bf16* __restrict__ Ob) {
  __shared__ bf16 Kl[64 * 64];            // [t][d], chunk-XOR swizzled (8 KB)
  __shared__ bf16 Vl[64 * 64];            // [d][t], chunk-XOR swizzled (8 KB)
  int bx = blockIdx.x;
  int xcd = bx & 7, j = bx >> 3;
  int g = xcd + 8 * (j / 25);             // (b,h) group 0..47, fixed per XCD
  int qblk = j % 25;
  int h = g % 6;
  int b = g / 6;
  int tid = threadIdx.x, w = tid >> 6, lane = tid & 63;
  int l32 = lane & 31, hi = lane >> 5;
  int q0w = qblk * 128 + w * 32;

  // Q fragments, B-operand of 32x32x16: n=lane&31=q, k=hi*8+j -> d=kk*16+hi*8+j
  bf16x8 qf[4];
  {
    int qi = q0w + l32;
    qi = qi < T1 ? qi : T1 - 1;
    const bf16* qp = &Qp[((size_t)b * T1 + qi) * DIM + h * 64];
#pragma unroll
    for (int kk = 0; kk < 4; ++kk) qf[kk] = *(const bf16x8*)&qp[kk * 16 + hi * 8];
  }
  floatx16 oacc[2];
  oacc[0] = (floatx16)0.f;
  oacc[1] = (floatx16)0.f;
  float lsum = 0.f;

  int rsub = lane >> 3;
  int chnk = (lane & 7) ^ rsub;
  const bf16* kg0 = &Kp[((size_t)b * T2 + w * 16 + rsub) * DIM + h * 64 + chnk * 8];
  const bf16* kg1 = kg0 + (size_t)8 * DIM;
  const bf16* vg0 = &Vt[((size_t)b * DIM + h * 64 + w * 16 + rsub) * T2P + chnk * 8];
  const bf16* vg1 = vg0 + (size_t)8 * T2P;
  bf16* kl0 = &Kl[(w * 16) * 64];
  bf16* kl1 = &Kl[(w * 16 + 8) * 64];
  bf16* vl0 = &Vl[(w * 16) * 64];
  bf16* vl1 = &Vl[(w * 16 + 8) * 64];

  int key = lane & 7;                     // fragment-read swizzle key (= row&7)

  for (int it = 0; it < 12; ++it) {
    __syncthreads();                      // prev iter's tile reads done
    gload_lds16(kg0, kl0);
    gload_lds16(kg1, kl1);
    gload_lds16(vg0, vl0);
    gload_lds16(vg1, vl1);
    __syncthreads();                      // drains vmcnt: tiles ready
#pragma unroll
    for (int tt = 0; tt < 2; ++tt) {      // two 32-t tiles
      floatx16 s = (floatx16)0.f;
#pragma unroll
      for (int kk = 0; kk < 4; ++kk) {    // d = kk*16 + hi*8 + j
        bf16x8 kf = *(const bf16x8*)&Kl[(tt * 32 + l32) * 64 + ((kk * 2 + hi) ^ key) * 8];
        s = MFMA32(kf, qf[kk], s);
      }
      float e[16];
#pragma unroll
      for (int r = 0; r < 16; ++r) {
        e[r] = __builtin_amdgcn_exp2f(s[r]);
        lsum += e[r];
      }
#pragma unroll
      for (int kkl = 0; kkl < 2; ++kkl) {
        int r0 = kkl * 8;
        u32 pA = pk2(e[r0 + 0], e[r0 + 1]);
        u32 pB = pk2(e[r0 + 2], e[r0 + 3]);
        u32 pC = pk2(e[r0 + 4], e[r0 + 5]);
        u32 pD = pk2(e[r0 + 6], e[r0 + 7]);
        u32 sA = __shfl_xor(pA, 32);
        u32 sB = __shfl_xor(pB, 32);
        u32 sC = __shfl_xor(pC, 32);
        u32 sD = __shfl_xor(pD, 32);
        union { u32 u[4]; bf16x8 v; } pf;
        pf.u[0] = hi ? sC : pA;
        pf.u[1] = hi ? sD : pB;
        pf.u[2] = hi ? pC : sA;
        pf.u[3] = hi ? pD : sB;
        int kk = tt * 2 + kkl;            // t-chunk for V: t = kk*16 + hi*8 + j
#pragma unroll
        for (int dt = 0; dt < 2; ++dt) {
          bf16x8 vf = *(const bf16x8*)&Vl[(dt * 32 + l32) * 64 + ((kk * 2 + hi) ^ key) * 8];
          oacc[dt] = MFMA32(vf, pf.v, oacc[dt]);
        }
      }
    }
    kg0 += (size_t)64 * DIM; kg1 += (size_t)64 * DIM;
    vg0 += 64; vg1 += 64;
  }
  // tail: t 768..783 (16 rows land in reg group r0..7; clamped rows never consumed)
  {
    int tq = 768 + l32;
    tq = tq < T2 ? tq : T2 - 1;
    const bf16* kp2 = &Kp[((size_t)b * T2 + tq) * DIM + h * 64];
    floatx16 s = (floatx16)0.f;
#pragma unroll
    for (int kk = 0; kk < 4; ++kk) {
      bf16x8 kf = *(const bf16x8*)&kp2[kk * 16 + hi * 8];
      s = MFMA32(kf, qf[kk], s);
    }
    float e[8];
#pragma unroll
    for (int r = 0; r < 8; ++r) {
      e[r] = __builtin_amdgcn_exp2f(s[r]);
      lsum += e[r];
    }
    u32 pA = pk2(e[0], e[1]);
    u32 pB = pk2(e[2], e[3]);
    u32 pC = pk2(e[4], e[5]);
    u32 pD = pk2(e[6], e[7]);
    u32 sA = __shfl_xor(pA, 32);
    u32 sB = __shfl_xor(pB, 32);
    u32 sC = __shfl_xor(pC, 32);
    u32 sD = __shfl_xor(pD, 32);
    union { u32 u[4]; bf16x8 v; } pf;
    pf.u[0] = hi ? sC : pA;
    pf.u[1] = hi ? sD : pB;
    pf.u[2] = hi ? pC : sA;
    pf.u[3] = hi ? pD : sB;
#pragma unroll
    for (int dt = 0; dt < 2; ++dt) {
      const bf16* vp2 = &Vt[((size_t)b * DIM + h * 64 + dt * 32 + l32) * T2P + 768 + hi * 8];
      bf16x8 vf = *(const bf16x8*)vp2;
      oacc[dt] = MFMA32(vf, pf.v, oacc[dt]);
    }
  }
  // epilogue
  lsum += __shfl_xor(lsum, 32);
  float inv = 1.f / lsum;
  int qg = q0w + l32;
  if (qg < T1) {
    bf16* op = &Ob[((size_t)b * T1 + qg) * DIM + h * 64];
#pragma unroll
    for (int dt = 0; dt < 2; ++dt) {
#pragma unroll
      for (int gr = 0; gr < 4; ++gr) {
        bf16x4 ov = (bf16x4){(bf16)(oacc[dt][gr * 4 + 0] * inv),
                             (bf16)(oacc[dt][gr * 4 + 1] * inv),
                             (bf16)(oacc[dt][gr * 4 + 2] * inv),
                             (bf16)(oacc[dt][gr * 4 + 3] * inv)};
        *(bf16x4*)&op[dt * 32 + gr * 8 + hi * 4] = ov;
      }
    }
  }
}

// ---------------- launch ----------------
extern "C" void kernel_launch(void* const* d_in, const int* in_sizes, int n_in,
                              void* d_out, int out_size, void* d_ws, size_t ws_size,
                              hipStream_t stream) {
  (void)in_sizes; (void)n_in; (void)out_size; (void)ws_size;
  const float* x      = (const float*)d_in[0];
  const float* conv_q = (const float*)d_in[3];
  const float* bnq_s  = (const float*)d_in[4];
  const float* bnq_b  = (const float*)d_in[5];
  const float* bnq_m  = (const float*)d_in[6];
  const float* bnq_v  = (const float*)d_in[7];
  const float* conv_k = (const float*)d_in[8];
  const float* bnk_s  = (const float*)d_in[9];
  const float* bnk_b  = (const float*)d_in[10];
  const float* bnk_m  = (const float*)d_in[11];
  const float* bnk_v  = (const float*)d_in[12];
  const float* conv_v = (const float*)d_in[13];
  const float* bnv_s  = (const float*)d_in[14];
  const float* bnv_b  = (const float*)d_in[15];
  const float* bnv_m  = (const float*)d_in[16];
  const float* bnv_v  = (const float*)d_in[17];
  const float* wq     = (const float*)d_in[18];
  const float* wk     = (const float*)d_in[19];
  const float* wv     = (const float*)d_in[20];
  const float* wl     = (const float*)d_in[21];
  const float* b_last = (const float*)d_in[22];

  char* ws = (char*)d_ws;
  bf16* q_act = (bf16*)(ws + 0);               // 19267584; reused as attention output
  bf16* k_act = (bf16*)(ws + 19267584);        // 4816896
  bf16* v_act = (bf16*)(ws + 24084480);        // 4816896
  bf16* Qp    = (bf16*)(ws + 28901376);        // 19267584 (pre-scaled by SCALE*log2e)
  bf16* Kp    = (bf16*)(ws + 48168960);        // 4816896
  bf16* Vtp   = (bf16*)(ws + 52985856);        // 8*384*832*2 = 5111808  [B][384][T2P]
  bf16* wqb   = (bf16*)(ws + 58097664);        // 294912 each, x4
  bf16* wkb   = wqb + 147456;
  bf16* wvb   = wkb + 147456;
  bf16* wlb   = wvb + 147456;

  const float QSCALE = 0.05103103630798288f * 1.4426950408889634f;  // 384^-0.5 * log2e

  conv_fused_kernel<<<B_ * 56 * 14, DIM, 0, stream>>>(
      x,
      conv_q, bnq_s, bnq_b, bnq_m, bnq_v,
      conv_k, bnk_s, bnk_b, bnk_m, bnk_v,
      conv_v, bnv_s, bnv_b, bnv_m, bnv_v,
      q_act, k_act, v_act,
      wq, wk, wv, wl, wqb, wkb, wvb, wlb);

  qkv_gemm_kernel<<<448, 512, 0, stream>>>(q_act, k_act, v_act, wqb, wkb, wvb,
                                           Qp, Kp, Vtp, QSCALE);

  attn_kernel<<<25 * 6 * B_, 256, 0, stream>>>(Qp, Kp, Vtp, q_act);

  last_gemm_kernel<<<296, 512, 0, stream>>>(q_act, wlb, (float*)d_out, b_last);
}